// Round 7
// baseline (1738.259 us; speedup 1.0000x reference)
//
#include <hip/hip_runtime.h>
#include <hip/hip_bf16.h>
#include <cstdint>
#include <cstddef>

#define N_NODES 50000
#define F_DIM   128
#define E_EDGES 800000
#define NNZ     (3 * E_EDGES)
#define NBINS   (3 * N_NODES)
#define BN_EPS  1e-5f

typedef __attribute__((ext_vector_type(8))) short short8;
typedef __attribute__((ext_vector_type(4))) float f32x4;
typedef unsigned short ushort_t;

__device__ __forceinline__ ushort_t f2b(float f) {
    union { float f; uint32_t u; } v; v.f = f;
    uint32_t u = v.u + 0x7fffu + ((v.u >> 16) & 1u);  // round-to-nearest-even
    return (ushort_t)(u >> 16);
}
__device__ __forceinline__ float b2f_lo(uint32_t u) { union { uint32_t u; float f; } v; v.u = u << 16; return v.f; }
__device__ __forceinline__ float b2f_hi(uint32_t u) { union { uint32_t u; float f; } v; v.u = u & 0xffff0000u; return v.f; }
__device__ __forceinline__ uint32_t pk2b(float lo, float hi) {
    return ((uint32_t)f2b(hi) << 16) | (uint32_t)f2b(lo);
}

// ---------------------------------------------------------------- prep: f32 -> bf16 weights
__global__ __launch_bounds__(256) void prep_kernel(
    const float* __restrict__ Wa1, const float* __restrict__ W0, const float* __restrict__ W1,
    ushort_t* __restrict__ Wa1b, ushort_t* __restrict__ W0b, ushort_t* __restrict__ W1b)
{
    int i = blockIdx.x * 256 + threadIdx.x;
    if (i < 3 * 16384) Wa1b[i] = f2b(Wa1[i]);
    if (i < 16384) { W0b[i] = f2b(W0[i]); W1b[i] = f2b(W1[i]); }
}

// ---------------------------------------------------------------- x (f32) -> xb (bf16)
__global__ __launch_bounds__(256) void x2b_kernel(const float* __restrict__ x, ushort_t* __restrict__ xb)
{
    int i = blockIdx.x * 256 + threadIdx.x;
    if (i >= N_NODES * 32) return;
    float4 v = ((const float4*)x)[i];
    ushort4 o;
    o.x = f2b(v.x); o.y = f2b(v.y); o.z = f2b(v.z); o.w = f2b(v.w);
    ((ushort4*)xb)[i] = o;
}

// ---------------------------------------------------------------- CSR build: bins keyed (set, col)
__global__ __launch_bounds__(256) void hist_kernel(
    const int* __restrict__ ei0, const int* __restrict__ ei1, const int* __restrict__ ei2,
    int* __restrict__ cnt)
{
    const int s = blockIdx.y;
    const int* ei = (s == 0) ? ei0 : ((s == 1) ? ei1 : ei2);
    int e = blockIdx.x * 256 + threadIdx.x;
    if (e < E_EDGES) atomicAdd(&cnt[s * N_NODES + ei[E_EDGES + e]], 1);
}

// shuffle-based block scan
__global__ __launch_bounds__(1024) void scan1_kernel(
    const int* __restrict__ cnt, int* __restrict__ offs, int* __restrict__ bsum)
{
    __shared__ int wsum[16];
    const int tid = threadIdx.x;
    const int lane = tid & 63;
    const int wv = tid >> 6;
    const int i = blockIdx.x * 1024 + tid;
    int v = (i < NBINS) ? cnt[i] : 0;
    int incl = v;
#pragma unroll
    for (int d = 1; d < 64; d <<= 1) {
        int t = __shfl_up(incl, d, 64);
        if (lane >= d) incl += t;
    }
    if (lane == 63) wsum[wv] = incl;
    __syncthreads();
    if (wv == 0 && lane < 16) {
        int w = wsum[lane];
        int wincl = w;
#pragma unroll
        for (int d = 1; d < 16; d <<= 1) {
            int t = __shfl_up(wincl, d, 64);
            if (lane >= d) wincl += t;
        }
        wsum[lane] = wincl - w;
    }
    __syncthreads();
    int full = incl + wsum[wv];
    if (i < NBINS) offs[i] = full - v;
    if (tid == 1023) bsum[blockIdx.x] = full;
}

__global__ __launch_bounds__(256) void scan2_kernel(int* __restrict__ bsum, int* __restrict__ offs, int nb)
{
    __shared__ int ls[256];
    const int tid = threadIdx.x;
    int v = (tid < nb) ? bsum[tid] : 0;
    ls[tid] = v;
    __syncthreads();
#pragma unroll
    for (int d = 1; d < 256; d <<= 1) {
        int t = (tid >= d) ? ls[tid - d] : 0;
        __syncthreads();
        ls[tid] += t;
        __syncthreads();
    }
    if (tid < nb) bsum[tid] = ls[tid] - v;
    if (tid == 255) offs[NBINS] = ls[255];
}

__global__ __launch_bounds__(1024) void scan3_kernel(
    int* __restrict__ offs, const int* __restrict__ bsum, int* __restrict__ cursor)
{
    const int i = blockIdx.x * 1024 + threadIdx.x;
    if (i < NBINS) {
        int o = offs[i] + bsum[blockIdx.x];
        offs[i] = o;
        cursor[i] = o;
    }
}

// fill CSR slots with (src, col); set s occupies global slots [s*E, (s+1)*E)
__global__ __launch_bounds__(256) void fill_kernel(
    const int* __restrict__ ei0, const int* __restrict__ ei1, const int* __restrict__ ei2,
    int* __restrict__ cursor, int2* __restrict__ csr)
{
    const int s = blockIdx.y;
    const int* ei = (s == 0) ? ei0 : ((s == 1) ? ei1 : ei2);
    int e = blockIdx.x * 256 + threadIdx.x;
    if (e >= E_EDGES) return;
    const int rn = ei[e];
    const int cn = ei[E_EDGES + e];
    int pos = atomicAdd(&cursor[s * N_NODES + cn], 1);
    csr[pos] = make_int2(rn, cn);
}

// ---------------------------------------------------------------- edge MLP, pipelined + slim
// Two 16-edge tiles per group processed SEQUENTIALLY (one tile's A-frags live at a time).
// Row gathers double-buffered (32 VGPRs); cols JIT per-kb (L1-resident via CSR order);
// B + bias + Wa2 from LDS. Target total regs (arch+acc) <= 128 -> 4 waves/SIMD, no spill.
__global__ __launch_bounds__(256, 4) void edge_mlp_kernel(
    const ushort_t* __restrict__ xb, int2* __restrict__ csr,
    const ushort_t* __restrict__ Wa1b, const float* __restrict__ ba1,
    const float* __restrict__ Wa2, const float* __restrict__ ba2,
    float* __restrict__ deg)
{
    __shared__ short8 Wlds[2048];   // 32 KB, fragment order [nb][kb][lane]
    __shared__ float bwlds[256];    // [0:128) bias, [128:256) Wa2
    const int s = blockIdx.y;
    const float b2 = ba2[s];
    int2* csr_s = csr + (size_t)s * E_EDGES;
    float* degs = deg + (size_t)s * N_NODES;

    const int tid = threadIdx.x;
    const int lane = tid & 63;
    const int quad = lane >> 4;
    const int lcol = lane & 15;

    {
        const ushort_t* W = Wa1b + s * 16384;
#pragma unroll
        for (int r = 0; r < 8; r++) {
            int c = tid + r * 256;
            int nbkb = c >> 6;
            int lc = c & 63;
            int nb = nbkb >> 2, kb = nbkb & 3;
            int q = lc >> 4, l = lc & 15;
            Wlds[c] = *(const short8*)(W + (nb * 16 + l) * 128 + kb * 32 + q * 8);
        }
        if (tid < 128) {
            bwlds[tid] = ba1[s * 128 + tid];
            bwlds[128 + tid] = Wa2[s * 128 + tid];
        }
    }
    __syncthreads();

    const int wid = blockIdx.x * 4 + (tid >> 6);
    const int nw = gridDim.x * 4;
    const int NG = E_EDGES / 32;   // 25000
    if (wid >= NG) return;

    int g = wid;
    int2 rec[2];
    short8 rraw[2][4];
#pragma unroll
    for (int t = 0; t < 2; t++) rec[t] = csr_s[g * 32 + t * 16 + lcol];
#pragma unroll
    for (int t = 0; t < 2; t++) {
        const ushort_t* xr = xb + (size_t)rec[t].x * 128 + quad * 8;
#pragma unroll
        for (int kb = 0; kb < 4; kb++) rraw[t][kb] = *(const short8*)(xr + kb * 32);
    }

    while (true) {
        const int gn = g + nw;
        const bool more = (gn < NG);
        int2 rec_next[2];
        if (more) {
            rec_next[0] = csr_s[gn * 32 + lcol];
            rec_next[1] = csr_s[gn * 32 + 16 + lcol];
        }

        float acc2[2][4];
#pragma unroll
        for (int t = 0; t < 2; t++) {
            // col JIT per-kb (L1 hit) + convert; frees rraw[t]
            short8 a[4];
            const ushort_t* xc = xb + (size_t)rec[t].y * 128 + quad * 8;
#pragma unroll
            for (int kb = 0; kb < 4; kb++) {
                short8 craw = *(const short8*)(xc + kb * 32);
                uint32_t* ru = (uint32_t*)&rraw[t][kb];
                uint32_t* cu = (uint32_t*)&craw;
                short8 dd;
                uint32_t* du = (uint32_t*)&dd;
#pragma unroll
                for (int j = 0; j < 4; j++) {
                    float dlo = fabsf(b2f_lo(ru[j]) - b2f_lo(cu[j]));
                    float dhi = fabsf(b2f_hi(ru[j]) - b2f_hi(cu[j]));
                    du[j] = pk2b(dlo, dhi);
                }
                a[kb] = dd;
            }
            // rraw[t] now free: issue next group's tile-t row gathers (stay in flight across MFMA)
            if (more) {
                const ushort_t* xr = xb + (size_t)rec_next[t].x * 128 + quad * 8;
#pragma unroll
                for (int kb = 0; kb < 4; kb++) rraw[t][kb] = *(const short8*)(xr + kb * 32);
            }
            // MFMA + hidden epilogue — B/bias/wv from LDS only, no VMEM waits here
            float af0 = 0.f, af1 = 0.f, af2 = 0.f, af3 = 0.f;
#pragma unroll
            for (int nb = 0; nb < 8; nb++) {
                f32x4 d = {0.f, 0.f, 0.f, 0.f};
#pragma unroll
                for (int kb = 0; kb < 4; kb++) {
                    short8 b = Wlds[(nb * 4 + kb) * 64 + lane];
                    d = __builtin_amdgcn_mfma_f32_16x16x32_bf16(a[kb], b, d, 0, 0, 0);
                }
                const float bias = bwlds[nb * 16 + lcol];
                const float wv = bwlds[128 + nb * 16 + lcol];
                float v0 = d[0] + bias; v0 = v0 > 0.f ? v0 : 0.f; af0 += v0 * wv;
                float v1 = d[1] + bias; v1 = v1 > 0.f ? v1 : 0.f; af1 += v1 * wv;
                float v2 = d[2] + bias; v2 = v2 > 0.f ? v2 : 0.f; af2 += v2 * wv;
                float v3 = d[3] + bias; v3 = v3 > 0.f ? v3 : 0.f; af3 += v3 * wv;
            }
            acc2[t][0] = af0; acc2[t][1] = af1; acc2[t][2] = af2; acc2[t][3] = af3;
        }

#pragma unroll
        for (int t = 0; t < 2; t++) {
#pragma unroll
            for (int r = 0; r < 4; r++)
#pragma unroll
                for (int m = 1; m < 16; m <<= 1) acc2[t][r] += __shfl_xor(acc2[t][r], m, 64);
            int cc = __shfl(rec[t].y, quad * 4 + (lane & 3), 64);
            if (lcol < 4) {
                float sv = (lcol == 0) ? acc2[t][0] : ((lcol == 1) ? acc2[t][1] : ((lcol == 2) ? acc2[t][2] : acc2[t][3]));
                float w = 1.f / (1.f + __expf(-(sv + b2)));
                const int ee = g * 32 + t * 16 + quad * 4 + lcol;
                csr_s[ee].y = __float_as_int(w);
                unsafeAtomicAdd(&degs[cc], w);
            }
        }

        if (!more) break;
        rec[0] = rec_next[0];
        rec[1] = rec_next[1];
        g = gn;
    }
}

// ---------------------------------------------------------------- dinv over all (set,node) bins
__global__ __launch_bounds__(256) void dinv_kernel(const float* __restrict__ deg,
                                                   float* __restrict__ dinv, int n)
{
    int i = blockIdx.x * 256 + threadIdx.x;
    if (i < n) {
        float d = deg[i];
        dinv[i] = d > 0.f ? rsqrtf(fmaxf(d, 1e-30f)) : 0.f;
    }
}

// ---------------------------------------------------------------- normalize per bin: y *= dinv[src]*dinv[col]
__global__ __launch_bounds__(256) void norm_kernel(
    int2* __restrict__ csr, const int* __restrict__ offs, const float* __restrict__ dinv)
{
    int bin = blockIdx.x * 256 + threadIdx.x;
    if (bin >= NBINS) return;
    const float dc = dinv[bin];
    const int base = (bin / N_NODES) * N_NODES;
    const int en = offs[bin + 1];
    for (int i = offs[bin]; i < en; i++) {
        int2 rec = csr[i];
        float w = __int_as_float(rec.y) * dc * dinv[base + rec.x];
        csr[i].y = __float_as_int(w);
    }
}

// ---------------------------------------------------------------- gather-SpMM, 3 segments, unroll-8
__global__ __launch_bounds__(256) void gather_spmm_kernel(
    const ushort_t* __restrict__ hb, const int* __restrict__ offs,
    const int2* __restrict__ edges, const float* __restrict__ bias,
    ushort_t* __restrict__ vb)
{
    const int wave = threadIdx.x >> 6;
    const int lane = threadIdx.x & 63;
    const int node = blockIdx.x * 4 + wave;
    if (node >= N_NODES) return;
    const int f = lane * 2;
    int st[3], en[3];
#pragma unroll
    for (int s = 0; s < 3; s++) {
        st[s] = offs[s * N_NODES + node];
        en[s] = offs[s * N_NODES + node + 1];
    }
    float ax = 0.f, ay = 0.f;
#pragma unroll
    for (int s = 0; s < 3; s++) {
        int e = st[s];
        const int end = en[s];
        for (; e + 8 <= end; e += 8) {
            int2 ev[8];
#pragma unroll
            for (int k = 0; k < 8; k++) ev[k] = edges[e + k];
            uint32_t u[8];
#pragma unroll
            for (int k = 0; k < 8; k++) u[k] = *(const uint32_t*)(hb + (size_t)ev[k].x * 128 + f);
#pragma unroll
            for (int k = 0; k < 8; k++) {
                float w = __int_as_float(ev[k].y);
                ax += w * b2f_lo(u[k]); ay += w * b2f_hi(u[k]);
            }
        }
        for (; e < end; e++) {
            int2 evv = edges[e];
            uint32_t u = *(const uint32_t*)(hb + (size_t)evv.x * 128 + f);
            float w = __int_as_float(evv.y);
            ax += w * b2f_lo(u); ay += w * b2f_hi(u);
        }
    }
    ax += 3.f * bias[f];     ax = ax > 0.f ? ax : 0.f;
    ay += 3.f * bias[f + 1]; ay = ay > 0.f ? ay : 0.f;
    *(uint32_t*)(vb + (size_t)node * 128 + f) = pk2b(ax, ay);
}

// ---------------------------------------------------------------- dense GEMM, bf16 in/out
__global__ __launch_bounds__(256) void gemm_rows_kernel(
    const ushort_t* __restrict__ Ab, const ushort_t* __restrict__ Wb,
    ushort_t* __restrict__ outb, int n)
{
    const int wave = threadIdx.x >> 6;
    const int lane = threadIdx.x & 63;
    const int quad = lane >> 4;
    const int lcol = lane & 15;
    const int i0 = (blockIdx.x * 4 + wave) * 16;
    if (i0 >= n) return;

    short8 a[4];
    const ushort_t* ar = Ab + (size_t)(i0 + lcol) * 128;
#pragma unroll
    for (int kb = 0; kb < 4; kb++) a[kb] = *(const short8*)(ar + kb * 32 + quad * 8);

#pragma unroll
    for (int nb = 0; nb < 8; nb++) {
        f32x4 d = {0.f, 0.f, 0.f, 0.f};
        const ushort_t* wp = Wb + (nb * 16 + lcol) * 128 + quad * 8;
#pragma unroll
        for (int kb = 0; kb < 4; kb++) {
            short8 b = *(const short8*)(wp + kb * 32);
            d = __builtin_amdgcn_mfma_f32_16x16x32_bf16(a[kb], b, d, 0, 0, 0);
        }
#pragma unroll
        for (int r = 0; r < 4; r++) {
            outb[(size_t)(i0 + quad * 4 + r) * 128 + nb * 16 + lcol] = f2b(d[r]);
        }
    }
}

// ---------------------------------------------------------------- GEMM with fused bn0+relu on A
__global__ __launch_bounds__(256) void gemm_bn_rows_kernel(
    const ushort_t* __restrict__ Ab, const float* __restrict__ scale, const float* __restrict__ shift,
    const ushort_t* __restrict__ Wb, ushort_t* __restrict__ outb, int n)
{
    const int wave = threadIdx.x >> 6;
    const int lane = threadIdx.x & 63;
    const int quad = lane >> 4;
    const int lcol = lane & 15;
    const int i0 = (blockIdx.x * 4 + wave) * 16;
    if (i0 >= n) return;

    short8 a[4];
    const ushort_t* ar = Ab + (size_t)(i0 + lcol) * 128;
#pragma unroll
    for (int kb = 0; kb < 4; kb++) {
        short8 raw = *(const short8*)(ar + kb * 32 + quad * 8);
        uint32_t* ru = (uint32_t*)&raw;
        short8 t;
        uint32_t* tu = (uint32_t*)&t;
#pragma unroll
        for (int j = 0; j < 4; j++) {
            const int k = kb * 32 + quad * 8 + 2 * j;
            float lo = b2f_lo(ru[j]) * scale[k] + shift[k];
            float hi = b2f_hi(ru[j]) * scale[k + 1] + shift[k + 1];
            lo = lo > 0.f ? lo : 0.f;
            hi = hi > 0.f ? hi : 0.f;
            tu[j] = pk2b(lo, hi);
        }
        a[kb] = t;
    }

#pragma unroll
    for (int nb = 0; nb < 8; nb++) {
        f32x4 d = {0.f, 0.f, 0.f, 0.f};
        const ushort_t* wp = Wb + (nb * 16 + lcol) * 128 + quad * 8;
#pragma unroll
        for (int kb = 0; kb < 4; kb++) {
            short8 b = *(const short8*)(wp + kb * 32);
            d = __builtin_amdgcn_mfma_f32_16x16x32_bf16(a[kb], b, d, 0, 0, 0);
        }
#pragma unroll
        for (int r = 0; r < 4; r++) {
            outb[(size_t)(i0 + quad * 4 + r) * 128 + nb * 16 + lcol] = f2b(d[r]);
        }
    }
}

// ---------------------------------------------------------------- per-feature sum/sumsq of bf16 v
__global__ __launch_bounds__(256) void stats_kernel(
    const ushort_t* __restrict__ vb, float* __restrict__ sums)
{
    __shared__ float lsx[256], lsy[256], l2x[256], l2y[256];
    float sx = 0.f, sy = 0.f, s2x = 0.f, s2y = 0.f;
    const uint32_t* vu = (const uint32_t*)vb;
    const long total = (long)N_NODES * 64;
    const long stride = (long)gridDim.x * 256;
    for (long i = (long)blockIdx.x * 256 + threadIdx.x; i < total; i += stride) {
        uint32_t u = vu[i];
        float lo = b2f_lo(u), hi = b2f_hi(u);
        sx += lo; sy += hi; s2x += lo * lo; s2y += hi * hi;
    }
    lsx[threadIdx.x] = sx; lsy[threadIdx.x] = sy;
    l2x[threadIdx.x] = s2x; l2y[threadIdx.x] = s2y;
    __syncthreads();
    if (threadIdx.x < 64) {
        const int t = threadIdx.x;
        sx  = lsx[t] + lsx[t + 64] + lsx[t + 128] + lsx[t + 192];
        sy  = lsy[t] + lsy[t + 64] + lsy[t + 128] + lsy[t + 192];
        s2x = l2x[t] + l2x[t + 64] + l2x[t + 128] + l2x[t + 192];
        s2y = l2y[t] + l2y[t + 64] + l2y[t + 128] + l2y[t + 192];
        const int f = t * 2;
        unsafeAtomicAdd(&sums[f], sx);
        unsafeAtomicAdd(&sums[f + 1], sy);
        unsafeAtomicAdd(&sums[128 + f], s2x);
        unsafeAtomicAdd(&sums[128 + f + 1], s2y);
    }
}

// bn -> scale/shift form: val*scale + shift == (val-mu)*rstd*gamma + beta
__global__ void finalize_stats_kernel(const float* __restrict__ sums,
                                      const float* __restrict__ gamma, const float* __restrict__ beta,
                                      float* __restrict__ scale, float* __restrict__ shift)
{
    int f = threadIdx.x;
    float m = sums[f] / (float)N_NODES;
    float var = sums[128 + f] / (float)N_NODES - m * m;
    float rs = rsqrtf(var + BN_EPS);
    float sc = rs * gamma[f];
    scale[f] = sc;
    shift[f] = beta[f] - m * sc;
}

// ---------------------------------------------------------------- final: out = bn1(v) + x
__global__ __launch_bounds__(256) void bn_final_kernel(
    const ushort_t* __restrict__ vb, const float* __restrict__ scale, const float* __restrict__ shift,
    const float* __restrict__ xres, float* __restrict__ outf)
{
    const uint32_t* vu = (const uint32_t*)vb;
    const long total = (long)N_NODES * 64;
    const long stride = (long)gridDim.x * 256;
    for (long i = (long)blockIdx.x * 256 + threadIdx.x; i < total; i += stride) {
        const int f = ((int)(i & 63)) * 2;
        uint32_t u = vu[i];
        float2 xr = ((const float2*)xres)[i];
        float lo = b2f_lo(u) * scale[f] + shift[f] + xr.x;
        float hi = b2f_hi(u) * scale[f + 1] + shift[f + 1] + xr.y;
        ((float2*)outf)[i] = make_float2(lo, hi);
    }
}

// ----------------------------------------------------------------
extern "C" void kernel_launch(void* const* d_in, const int* in_sizes, int n_in,
                              void* d_out, int out_size, void* d_ws, size_t ws_size,
                              hipStream_t stream)
{
    const float* x   = (const float*)d_in[0];
    const int* ei0   = (const int*)d_in[1];
    const int* ei1   = (const int*)d_in[2];
    const int* ei2   = (const int*)d_in[3];
    const float* Wa1 = (const float*)d_in[4];
    const float* ba1 = (const float*)d_in[5];
    const float* Wa2 = (const float*)d_in[6];
    const float* ba2 = (const float*)d_in[7];
    const float* W0  = (const float*)d_in[8];
    const float* b0  = (const float*)d_in[9];
    const float* W1  = (const float*)d_in[10];
    const float* b1  = (const float*)d_in[11];
    const float* g0  = (const float*)d_in[12];
    const float* be0 = (const float*)d_in[13];
    const float* g1  = (const float*)d_in[14];
    const float* be1 = (const float*)d_in[15];
    float* out = (float*)d_out;

    char* ws = (char*)d_ws;
    size_t off = 0;
    auto alloc = [&](size_t bytes) -> void* {
        void* p = ws + off;
        off += (bytes + 255) & ~(size_t)255;
        return p;
    };
    ushort_t* Wa1b = (ushort_t*)alloc(3 * 16384 * 2);
    ushort_t* W0b  = (ushort_t*)alloc(16384 * 2);
    ushort_t* W1b  = (ushort_t*)alloc(16384 * 2);
    float* deg   = (float*)alloc((size_t)NBINS * 4);
    float* dinv  = (float*)alloc((size_t)NBINS * 4);
    int*   cnt   = (int*)alloc((size_t)NBINS * 4);
    int*   offs  = (int*)alloc(((size_t)NBINS + 1) * 4);
    int*   cursor= (int*)alloc((size_t)NBINS * 4);
    int*   bsum  = (int*)alloc(256 * 4);
    int2*  csr   = (int2*)alloc((size_t)NNZ * 8);
    ushort_t* xb  = (ushort_t*)alloc((size_t)N_NODES * 128 * 2);
    ushort_t* hb  = (ushort_t*)alloc((size_t)N_NODES * 128 * 2);
    ushort_t* vb0 = (ushort_t*)alloc((size_t)N_NODES * 128 * 2);
    ushort_t* vb1 = (ushort_t*)alloc((size_t)N_NODES * 128 * 2);
    float* sums0 = (float*)alloc(256 * 4);
    float* sums1 = (float*)alloc(256 * 4);
    float* sc0 = (float*)alloc(128 * 4);
    float* sh0 = (float*)alloc(128 * 4);
    float* sc1 = (float*)alloc(128 * 4);
    float* sh1 = (float*)alloc(128 * 4);
    (void)ws_size; (void)in_sizes; (void)n_in; (void)out_size;

    hipMemsetAsync(deg, 0, (size_t)NBINS * 4, stream);
    hipMemsetAsync(cnt, 0, (size_t)NBINS * 4, stream);
    hipMemsetAsync(sums0, 0, 256 * 4, stream);
    hipMemsetAsync(sums1, 0, 256 * 4, stream);

    prep_kernel<<<192, 256, 0, stream>>>(Wa1, W0, W1, Wa1b, W0b, W1b);
    x2b_kernel<<<6250, 256, 0, stream>>>(x, xb);

    // CSR by (set, dest)
    const int nscan = (NBINS + 1023) / 1024;  // 147
    hist_kernel<<<dim3(3125, 3), 256, 0, stream>>>(ei0, ei1, ei2, cnt);
    scan1_kernel<<<nscan, 1024, 0, stream>>>(cnt, offs, bsum);
    scan2_kernel<<<1, 256, 0, stream>>>(bsum, offs, nscan);
    scan3_kernel<<<nscan, 1024, 0, stream>>>(offs, bsum, cursor);
    fill_kernel<<<dim3(3125, 3), 256, 0, stream>>>(ei0, ei1, ei2, cursor, csr);

    // pipelined edge MLP
    edge_mlp_kernel<<<dim3(782, 3), 256, 0, stream>>>(xb, csr, Wa1b, ba1, Wa2, ba2, deg);
    dinv_kernel<<<(NBINS + 255) / 256, 256, 0, stream>>>(deg, dinv, NBINS);
    norm_kernel<<<(NBINS + 255) / 256, 256, 0, stream>>>(csr, offs, dinv);

    // layer 0
    gemm_rows_kernel<<<782, 256, 0, stream>>>(xb, W0b, hb, N_NODES);
    gather_spmm_kernel<<<12500, 256, 0, stream>>>(hb, offs, csr, b0, vb0);
    stats_kernel<<<512, 256, 0, stream>>>(vb0, sums0);
    finalize_stats_kernel<<<1, 128, 0, stream>>>(sums0, g0, be0, sc0, sh0);

    // layer 1 (bn0+relu fused into A-fragment construction)
    gemm_bn_rows_kernel<<<782, 256, 0, stream>>>(vb0, sc0, sh0, W1b, hb, N_NODES);
    gather_spmm_kernel<<<12500, 256, 0, stream>>>(hb, offs, csr, b1, vb1);
    stats_kernel<<<512, 256, 0, stream>>>(vb1, sums1);
    finalize_stats_kernel<<<1, 128, 0, stream>>>(sums1, g1, be1, sc1, sh1);
    bn_final_kernel<<<512, 256, 0, stream>>>(vb1, sc1, sh1, x, out);
}

// Round 8
// 1058.076 us; speedup vs baseline: 1.6428x; 1.6428x over previous
//
#include <hip/hip_runtime.h>
#include <hip/hip_bf16.h>
#include <cstdint>
#include <cstddef>

#define N_NODES 50000
#define F_DIM   128
#define E_EDGES 800000
#define NNZ     (3 * E_EDGES)
#define NBINS   (3 * N_NODES)
#define BN_EPS  1e-5f

typedef __attribute__((ext_vector_type(8))) short short8;
typedef __attribute__((ext_vector_type(4))) float f32x4;
typedef unsigned short ushort_t;

__device__ __forceinline__ ushort_t f2b(float f) {
    union { float f; uint32_t u; } v; v.f = f;
    uint32_t u = v.u + 0x7fffu + ((v.u >> 16) & 1u);  // round-to-nearest-even
    return (ushort_t)(u >> 16);
}
__device__ __forceinline__ float b2f_lo(uint32_t u) { union { uint32_t u; float f; } v; v.u = u << 16; return v.f; }
__device__ __forceinline__ float b2f_hi(uint32_t u) { union { uint32_t u; float f; } v; v.u = u & 0xffff0000u; return v.f; }
__device__ __forceinline__ uint32_t pk2b(float lo, float hi) {
    return ((uint32_t)f2b(hi) << 16) | (uint32_t)f2b(lo);
}

// ---------------------------------------------------------------- prep: f32 -> bf16 weights
__global__ __launch_bounds__(256) void prep_kernel(
    const float* __restrict__ Wa1, const float* __restrict__ W0, const float* __restrict__ W1,
    ushort_t* __restrict__ Wa1b, ushort_t* __restrict__ W0b, ushort_t* __restrict__ W1b)
{
    int i = blockIdx.x * 256 + threadIdx.x;
    if (i < 3 * 16384) Wa1b[i] = f2b(Wa1[i]);
    if (i < 16384) { W0b[i] = f2b(W0[i]); W1b[i] = f2b(W1[i]); }
}

// ---------------------------------------------------------------- x (f32) -> xb (bf16)
__global__ __launch_bounds__(256) void x2b_kernel(const float* __restrict__ x, ushort_t* __restrict__ xb)
{
    int i = blockIdx.x * 256 + threadIdx.x;
    if (i >= N_NODES * 32) return;
    float4 v = ((const float4*)x)[i];
    ushort4 o;
    o.x = f2b(v.x); o.y = f2b(v.y); o.z = f2b(v.z); o.w = f2b(v.w);
    ((ushort4*)xb)[i] = o;
}

// ---------------------------------------------------------------- CSR build: bins keyed (set, col)
__global__ __launch_bounds__(256) void hist_kernel(
    const int* __restrict__ ei0, const int* __restrict__ ei1, const int* __restrict__ ei2,
    int* __restrict__ cnt)
{
    const int s = blockIdx.y;
    const int* ei = (s == 0) ? ei0 : ((s == 1) ? ei1 : ei2);
    int e = blockIdx.x * 256 + threadIdx.x;
    if (e < E_EDGES) atomicAdd(&cnt[s * N_NODES + ei[E_EDGES + e]], 1);
}

// shuffle-based block scan
__global__ __launch_bounds__(1024) void scan1_kernel(
    const int* __restrict__ cnt, int* __restrict__ offs, int* __restrict__ bsum)
{
    __shared__ int wsum[16];
    const int tid = threadIdx.x;
    const int lane = tid & 63;
    const int wv = tid >> 6;
    const int i = blockIdx.x * 1024 + tid;
    int v = (i < NBINS) ? cnt[i] : 0;
    int incl = v;
#pragma unroll
    for (int d = 1; d < 64; d <<= 1) {
        int t = __shfl_up(incl, d, 64);
        if (lane >= d) incl += t;
    }
    if (lane == 63) wsum[wv] = incl;
    __syncthreads();
    if (wv == 0 && lane < 16) {
        int w = wsum[lane];
        int wincl = w;
#pragma unroll
        for (int d = 1; d < 16; d <<= 1) {
            int t = __shfl_up(wincl, d, 64);
            if (lane >= d) wincl += t;
        }
        wsum[lane] = wincl - w;
    }
    __syncthreads();
    int full = incl + wsum[wv];
    if (i < NBINS) offs[i] = full - v;
    if (tid == 1023) bsum[blockIdx.x] = full;
}

__global__ __launch_bounds__(256) void scan2_kernel(int* __restrict__ bsum, int* __restrict__ offs, int nb)
{
    __shared__ int ls[256];
    const int tid = threadIdx.x;
    int v = (tid < nb) ? bsum[tid] : 0;
    ls[tid] = v;
    __syncthreads();
#pragma unroll
    for (int d = 1; d < 256; d <<= 1) {
        int t = (tid >= d) ? ls[tid - d] : 0;
        __syncthreads();
        ls[tid] += t;
        __syncthreads();
    }
    if (tid < nb) bsum[tid] = ls[tid] - v;
    if (tid == 255) offs[NBINS] = ls[255];
}

__global__ __launch_bounds__(1024) void scan3_kernel(
    int* __restrict__ offs, const int* __restrict__ bsum, int* __restrict__ cursor)
{
    const int i = blockIdx.x * 1024 + threadIdx.x;
    if (i < NBINS) {
        int o = offs[i] + bsum[blockIdx.x];
        offs[i] = o;
        cursor[i] = o;
    }
}

// fill CSR slots with (src, col); set s occupies global slots [s*E, (s+1)*E)
__global__ __launch_bounds__(256) void fill_kernel(
    const int* __restrict__ ei0, const int* __restrict__ ei1, const int* __restrict__ ei2,
    int* __restrict__ cursor, int2* __restrict__ csr)
{
    const int s = blockIdx.y;
    const int* ei = (s == 0) ? ei0 : ((s == 1) ? ei1 : ei2);
    int e = blockIdx.x * 256 + threadIdx.x;
    if (e >= E_EDGES) return;
    const int rn = ei[e];
    const int cn = ei[E_EDGES + e];
    int pos = atomicAdd(&cursor[s * N_NODES + cn], 1);
    csr[pos] = make_int2(rn, cn);
}

// ---------------------------------------------------------------- edge MLP, pipelined (r5-measured 388us version)
// Rows+cols prefetched one group ahead; B from LDS; bias/Wa2 hoisted to registers.
// NO min-waves launch bound — forcing 4 waves/EU provably spills (r6/r7: WRITE_SIZE ~1 GB).
__global__ __launch_bounds__(256) void edge_mlp_kernel(
    const ushort_t* __restrict__ xb, int2* __restrict__ csr,
    const ushort_t* __restrict__ Wa1b, const float* __restrict__ ba1,
    const float* __restrict__ Wa2, const float* __restrict__ ba2,
    float* __restrict__ deg)
{
    __shared__ short8 Wlds[2048];   // 32 KB, fragment order [nb][kb][lane]
    const int s = blockIdx.y;
    const float* b1v = ba1 + s * 128;
    const float* w2v = Wa2 + s * 128;
    const float b2 = ba2[s];
    int2* csr_s = csr + (size_t)s * E_EDGES;
    float* degs = deg + (size_t)s * N_NODES;

    const int tid = threadIdx.x;
    const int lane = tid & 63;
    const int quad = lane >> 4;
    const int lcol = lane & 15;

    {
        const ushort_t* W = Wa1b + s * 16384;
#pragma unroll
        for (int r = 0; r < 8; r++) {
            int c = tid + r * 256;
            int nbkb = c >> 6;
            int lc = c & 63;
            int nb = nbkb >> 2, kb = nbkb & 3;
            int q = lc >> 4, l = lc & 15;
            Wlds[c] = *(const short8*)(W + (nb * 16 + l) * 128 + kb * 32 + q * 8);
        }
    }
    __syncthreads();

    float bias_r[8], wv_r[8];
#pragma unroll
    for (int nb = 0; nb < 8; nb++) {
        bias_r[nb] = b1v[nb * 16 + lcol];
        wv_r[nb]   = w2v[nb * 16 + lcol];
    }

    const int wid = blockIdx.x * 4 + (tid >> 6);
    const int nw = gridDim.x * 4;
    const int NG = E_EDGES / 32;   // 25000
    if (wid >= NG) return;

    int g = wid;
    int2 rec[2];
    rec[0] = csr_s[g * 32 + lcol];
    rec[1] = csr_s[g * 32 + 16 + lcol];
    short8 rraw[2][4], craw[2][4];
#pragma unroll
    for (int t = 0; t < 2; t++) {
        const ushort_t* xr = xb + (size_t)rec[t].x * 128 + quad * 8;
        const ushort_t* xc = xb + (size_t)rec[t].y * 128 + quad * 8;
#pragma unroll
        for (int kb = 0; kb < 4; kb++) {
            rraw[t][kb] = *(const short8*)(xr + kb * 32);
            craw[t][kb] = *(const short8*)(xc + kb * 32);
        }
    }

    while (true) {
        const int gn = g + nw;
        const bool more = (gn < NG);
        int2 rec_next[2];
        if (more) {
            rec_next[0] = csr_s[gn * 32 + lcol];
            rec_next[1] = csr_s[gn * 32 + 16 + lcol];
        }

        // convert current raw rows -> A fragments (bf16 |xr - xc|); frees rraw/craw
        short8 a[2][4];
#pragma unroll
        for (int t = 0; t < 2; t++)
#pragma unroll
        for (int kb = 0; kb < 4; kb++) {
            uint32_t* ru = (uint32_t*)&rraw[t][kb];
            uint32_t* cu = (uint32_t*)&craw[t][kb];
            short8 dd;
            uint32_t* du = (uint32_t*)&dd;
#pragma unroll
            for (int j = 0; j < 4; j++) {
                float dlo = fabsf(b2f_lo(ru[j]) - b2f_lo(cu[j]));
                float dhi = fabsf(b2f_hi(ru[j]) - b2f_hi(cu[j]));
                du[j] = pk2b(dlo, dhi);
            }
            a[t][kb] = dd;
        }

        // issue next group's gathers now; they stay in flight across the MFMA loop
        if (more) {
#pragma unroll
            for (int t = 0; t < 2; t++) {
                const ushort_t* xr = xb + (size_t)rec_next[t].x * 128 + quad * 8;
                const ushort_t* xc = xb + (size_t)rec_next[t].y * 128 + quad * 8;
#pragma unroll
                for (int kb = 0; kb < 4; kb++) {
                    rraw[t][kb] = *(const short8*)(xr + kb * 32);
                    craw[t][kb] = *(const short8*)(xc + kb * 32);
                }
            }
        }

        // MFMA + hidden-layer epilogue — no VMEM reads in here
        float acc[2][4] = {{0.f,0.f,0.f,0.f},{0.f,0.f,0.f,0.f}};
#pragma unroll
        for (int nb = 0; nb < 8; nb++) {
            short8 b[4];
#pragma unroll
            for (int kb = 0; kb < 4; kb++) b[kb] = Wlds[(nb * 4 + kb) * 64 + lane];
#pragma unroll
            for (int t = 0; t < 2; t++) {
                f32x4 d = {0.f, 0.f, 0.f, 0.f};
#pragma unroll
                for (int kb = 0; kb < 4; kb++)
                    d = __builtin_amdgcn_mfma_f32_16x16x32_bf16(a[t][kb], b[kb], d, 0, 0, 0);
#pragma unroll
                for (int r = 0; r < 4; r++) {
                    float v = d[r] + bias_r[nb];
                    v = v > 0.f ? v : 0.f;
                    acc[t][r] += v * wv_r[nb];
                }
            }
        }

#pragma unroll
        for (int t = 0; t < 2; t++) {
#pragma unroll
            for (int r = 0; r < 4; r++)
#pragma unroll
                for (int m = 1; m < 16; m <<= 1) acc[t][r] += __shfl_xor(acc[t][r], m, 64);
            int cc = __shfl(rec[t].y, quad * 4 + (lane & 3), 64);
            if (lcol < 4) {
                float sv = (lcol == 0) ? acc[t][0] : ((lcol == 1) ? acc[t][1] : ((lcol == 2) ? acc[t][2] : acc[t][3]));
                float w = 1.f / (1.f + __expf(-(sv + b2)));
                const int ee = g * 32 + t * 16 + quad * 4 + lcol;
                csr_s[ee].y = __float_as_int(w);   // raw sigmoid weight in place (col recoverable from bin)
                unsafeAtomicAdd(&degs[cc], w);
            }
        }

        if (!more) break;
        rec[0] = rec_next[0];
        rec[1] = rec_next[1];
        g = gn;
    }
}

// ---------------------------------------------------------------- dinv over all (set,node) bins
__global__ __launch_bounds__(256) void dinv_kernel(const float* __restrict__ deg,
                                                   float* __restrict__ dinv, int n)
{
    int i = blockIdx.x * 256 + threadIdx.x;
    if (i < n) {
        float d = deg[i];
        dinv[i] = d > 0.f ? rsqrtf(fmaxf(d, 1e-30f)) : 0.f;
    }
}

// ---------------------------------------------------------------- offs2[n] = combined (single-segment) offsets
__global__ __launch_bounds__(256) void offs2_kernel(const int* __restrict__ offs, int* __restrict__ offs2)
{
    int n = blockIdx.x * 256 + threadIdx.x;
    if (n <= N_NODES)
        offs2[n] = offs[n] + (offs[N_NODES + n] - E_EDGES) + (offs[2 * N_NODES + n] - 2 * E_EDGES);
}

// ---------------------------------------------------------------- repack: per-(set,col) CSR -> combined per-node
// segments with normalized weights. One wave per node; deterministic positions, no atomics.
__global__ __launch_bounds__(256) void repack_kernel(
    const int2* __restrict__ csr, const int* __restrict__ offs, const int* __restrict__ offs2,
    const float* __restrict__ dinv, int2* __restrict__ edges2)
{
    const int wave = threadIdx.x >> 6;
    const int lane = threadIdx.x & 63;
    const int node = blockIdx.x * 4 + wave;
    if (node >= N_NODES) return;

    int st0 = offs[node],                 c0 = offs[node + 1] - st0;
    int st1 = offs[N_NODES + node],       c1 = offs[N_NODES + node + 1] - st1;
    int st2 = offs[2 * N_NODES + node],   c2 = offs[2 * N_NODES + node + 1] - st2;
    const int L = c0 + c1 + c2;
    const int base2 = offs2[node];
    const float dc0 = dinv[node], dc1 = dinv[N_NODES + node], dc2 = dinv[2 * N_NODES + node];

    for (int j = lane; j < L; j += 64) {
        int i, sbase; float dc;
        if (j < c0)           { i = st0 + j;            sbase = 0;            dc = dc0; }
        else if (j < c0 + c1) { i = st1 + (j - c0);     sbase = N_NODES;      dc = dc1; }
        else                  { i = st2 + (j - c0 - c1); sbase = 2 * N_NODES; dc = dc2; }
        int2 rec = csr[i];
        float w = __int_as_float(rec.y) * dc * dinv[sbase + rec.x];
        edges2[base2 + j] = make_int2(rec.x, __float_as_int(w));
    }
}

// ---------------------------------------------------------------- gather-SpMM, single combined segment, unroll-8
__global__ __launch_bounds__(256) void gather_spmm_kernel(
    const ushort_t* __restrict__ hb, const int* __restrict__ offs2,
    const int2* __restrict__ edges, const float* __restrict__ bias,
    ushort_t* __restrict__ vb)
{
    const int wave = threadIdx.x >> 6;
    const int lane = threadIdx.x & 63;
    const int node = blockIdx.x * 4 + wave;
    if (node >= N_NODES) return;
    const int f = lane * 2;
    const int start = offs2[node];
    const int end   = offs2[node + 1];

    float ax = 0.f, ay = 0.f;
    int e = start;
    for (; e + 8 <= end; e += 8) {
        int2 ev[8];
#pragma unroll
        for (int k = 0; k < 8; k++) ev[k] = edges[e + k];
        uint32_t u[8];
#pragma unroll
        for (int k = 0; k < 8; k++) u[k] = *(const uint32_t*)(hb + (size_t)ev[k].x * 128 + f);
#pragma unroll
        for (int k = 0; k < 8; k++) {
            float w = __int_as_float(ev[k].y);
            ax += w * b2f_lo(u[k]); ay += w * b2f_hi(u[k]);
        }
    }
    for (; e < end; e++) {
        int2 evv = edges[e];
        uint32_t u = *(const uint32_t*)(hb + (size_t)evv.x * 128 + f);
        float w = __int_as_float(evv.y);
        ax += w * b2f_lo(u); ay += w * b2f_hi(u);
    }
    ax += 3.f * bias[f];     ax = ax > 0.f ? ax : 0.f;
    ay += 3.f * bias[f + 1]; ay = ay > 0.f ? ay : 0.f;
    *(uint32_t*)(vb + (size_t)node * 128 + f) = pk2b(ax, ay);
}

// ---------------------------------------------------------------- dense GEMM, bf16 in/out
__global__ __launch_bounds__(256) void gemm_rows_kernel(
    const ushort_t* __restrict__ Ab, const ushort_t* __restrict__ Wb,
    ushort_t* __restrict__ outb, int n)
{
    const int wave = threadIdx.x >> 6;
    const int lane = threadIdx.x & 63;
    const int quad = lane >> 4;
    const int lcol = lane & 15;
    const int i0 = (blockIdx.x * 4 + wave) * 16;
    if (i0 >= n) return;

    short8 a[4];
    const ushort_t* ar = Ab + (size_t)(i0 + lcol) * 128;
#pragma unroll
    for (int kb = 0; kb < 4; kb++) a[kb] = *(const short8*)(ar + kb * 32 + quad * 8);

#pragma unroll
    for (int nb = 0; nb < 8; nb++) {
        f32x4 d = {0.f, 0.f, 0.f, 0.f};
        const ushort_t* wp = Wb + (nb * 16 + lcol) * 128 + quad * 8;
#pragma unroll
        for (int kb = 0; kb < 4; kb++) {
            short8 b = *(const short8*)(wp + kb * 32);
            d = __builtin_amdgcn_mfma_f32_16x16x32_bf16(a[kb], b, d, 0, 0, 0);
        }
#pragma unroll
        for (int r = 0; r < 4; r++) {
            outb[(size_t)(i0 + quad * 4 + r) * 128 + nb * 16 + lcol] = f2b(d[r]);
        }
    }
}

// ---------------------------------------------------------------- GEMM with fused bn0+relu on A
__global__ __launch_bounds__(256) void gemm_bn_rows_kernel(
    const ushort_t* __restrict__ Ab, const float* __restrict__ scale, const float* __restrict__ shift,
    const ushort_t* __restrict__ Wb, ushort_t* __restrict__ outb, int n)
{
    const int wave = threadIdx.x >> 6;
    const int lane = threadIdx.x & 63;
    const int quad = lane >> 4;
    const int lcol = lane & 15;
    const int i0 = (blockIdx.x * 4 + wave) * 16;
    if (i0 >= n) return;

    short8 a[4];
    const ushort_t* ar = Ab + (size_t)(i0 + lcol) * 128;
#pragma unroll
    for (int kb = 0; kb < 4; kb++) {
        short8 raw = *(const short8*)(ar + kb * 32 + quad * 8);
        uint32_t* ru = (uint32_t*)&raw;
        short8 t;
        uint32_t* tu = (uint32_t*)&t;
#pragma unroll
        for (int j = 0; j < 4; j++) {
            const int k = kb * 32 + quad * 8 + 2 * j;
            float lo = b2f_lo(ru[j]) * scale[k] + shift[k];
            float hi = b2f_hi(ru[j]) * scale[k + 1] + shift[k + 1];
            lo = lo > 0.f ? lo : 0.f;
            hi = hi > 0.f ? hi : 0.f;
            tu[j] = pk2b(lo, hi);
        }
        a[kb] = t;
    }

#pragma unroll
    for (int nb = 0; nb < 8; nb++) {
        f32x4 d = {0.f, 0.f, 0.f, 0.f};
        const ushort_t* wp = Wb + (nb * 16 + lcol) * 128 + quad * 8;
#pragma unroll
        for (int kb = 0; kb < 4; kb++) {
            short8 b = *(const short8*)(wp + kb * 32);
            d = __builtin_amdgcn_mfma_f32_16x16x32_bf16(a[kb], b, d, 0, 0, 0);
        }
#pragma unroll
        for (int r = 0; r < 4; r++) {
            outb[(size_t)(i0 + quad * 4 + r) * 128 + nb * 16 + lcol] = f2b(d[r]);
        }
    }
}

// ---------------------------------------------------------------- per-feature sum/sumsq of bf16 v
__global__ __launch_bounds__(256) void stats_kernel(
    const ushort_t* __restrict__ vb, float* __restrict__ sums)
{
    __shared__ float lsx[256], lsy[256], l2x[256], l2y[256];
    float sx = 0.f, sy = 0.f, s2x = 0.f, s2y = 0.f;
    const uint32_t* vu = (const uint32_t*)vb;
    const long total = (long)N_NODES * 64;
    const long stride = (long)gridDim.x * 256;
    for (long i = (long)blockIdx.x * 256 + threadIdx.x; i < total; i += stride) {
        uint32_t u = vu[i];
        float lo = b2f_lo(u), hi = b2f_hi(u);
        sx += lo; sy += hi; s2x += lo * lo; s2y += hi * hi;
    }
    lsx[threadIdx.x] = sx; lsy[threadIdx.x] = sy;
    l2x[threadIdx.x] = s2x; l2y[threadIdx.x] = s2y;
    __syncthreads();
    if (threadIdx.x < 64) {
        const int t = threadIdx.x;
        sx  = lsx[t] + lsx[t + 64] + lsx[t + 128] + lsx[t + 192];
        sy  = lsy[t] + lsy[t + 64] + lsy[t + 128] + lsy[t + 192];
        s2x = l2x[t] + l2x[t + 64] + l2x[t + 128] + l2x[t + 192];
        s2y = l2y[t] + l2y[t + 64] + l2y[t + 128] + l2y[t + 192];
        const int f = t * 2;
        unsafeAtomicAdd(&sums[f], sx);
        unsafeAtomicAdd(&sums[f + 1], sy);
        unsafeAtomicAdd(&sums[128 + f], s2x);
        unsafeAtomicAdd(&sums[128 + f + 1], s2y);
    }
}

// bn -> scale/shift form: val*scale + shift == (val-mu)*rstd*gamma + beta
__global__ void finalize_stats_kernel(const float* __restrict__ sums,
                                      const float* __restrict__ gamma, const float* __restrict__ beta,
                                      float* __restrict__ scale, float* __restrict__ shift)
{
    int f = threadIdx.x;
    float m = sums[f] / (float)N_NODES;
    float var = sums[128 + f] / (float)N_NODES - m * m;
    float rs = rsqrtf(var + BN_EPS);
    float sc = rs * gamma[f];
    scale[f] = sc;
    shift[f] = beta[f] - m * sc;
}

// ---------------------------------------------------------------- final: out = bn1(v) + x
__global__ __launch_bounds__(256) void bn_final_kernel(
    const ushort_t* __restrict__ vb, const float* __restrict__ scale, const float* __restrict__ shift,
    const float* __restrict__ xres, float* __restrict__ outf)
{
    const uint32_t* vu = (const uint32_t*)vb;
    const long total = (long)N_NODES * 64;
    const long stride = (long)gridDim.x * 256;
    for (long i = (long)blockIdx.x * 256 + threadIdx.x; i < total; i += stride) {
        const int f = ((int)(i & 63)) * 2;
        uint32_t u = vu[i];
        float2 xr = ((const float2*)xres)[i];
        float lo = b2f_lo(u) * scale[f] + shift[f] + xr.x;
        float hi = b2f_hi(u) * scale[f + 1] + shift[f + 1] + xr.y;
        ((float2*)outf)[i] = make_float2(lo, hi);
    }
}

// ----------------------------------------------------------------
extern "C" void kernel_launch(void* const* d_in, const int* in_sizes, int n_in,
                              void* d_out, int out_size, void* d_ws, size_t ws_size,
                              hipStream_t stream)
{
    const float* x   = (const float*)d_in[0];
    const int* ei0   = (const int*)d_in[1];
    const int* ei1   = (const int*)d_in[2];
    const int* ei2   = (const int*)d_in[3];
    const float* Wa1 = (const float*)d_in[4];
    const float* ba1 = (const float*)d_in[5];
    const float* Wa2 = (const float*)d_in[6];
    const float* ba2 = (const float*)d_in[7];
    const float* W0  = (const float*)d_in[8];
    const float* b0  = (const float*)d_in[9];
    const float* W1  = (const float*)d_in[10];
    const float* b1  = (const float*)d_in[11];
    const float* g0  = (const float*)d_in[12];
    const float* be0 = (const float*)d_in[13];
    const float* g1  = (const float*)d_in[14];
    const float* be1 = (const float*)d_in[15];
    float* out = (float*)d_out;

    char* ws = (char*)d_ws;
    size_t off = 0;
    auto alloc = [&](size_t bytes) -> void* {
        void* p = ws + off;
        off += (bytes + 255) & ~(size_t)255;
        return p;
    };
    ushort_t* Wa1b = (ushort_t*)alloc(3 * 16384 * 2);
    ushort_t* W0b  = (ushort_t*)alloc(16384 * 2);
    ushort_t* W1b  = (ushort_t*)alloc(16384 * 2);
    float* deg    = (float*)alloc((size_t)NBINS * 4);
    float* dinv   = (float*)alloc((size_t)NBINS * 4);
    int*   cnt    = (int*)alloc((size_t)NBINS * 4);
    int*   offs   = (int*)alloc(((size_t)NBINS + 1) * 4);
    int*   offs2  = (int*)alloc(((size_t)N_NODES + 1) * 4);
    int*   cursor = (int*)alloc((size_t)NBINS * 4);
    int*   bsum   = (int*)alloc(256 * 4);
    int2*  csr    = (int2*)alloc((size_t)NNZ * 8);
    int2*  edges2 = (int2*)alloc((size_t)NNZ * 8);
    ushort_t* xb  = (ushort_t*)alloc((size_t)N_NODES * 128 * 2);
    ushort_t* hb  = (ushort_t*)alloc((size_t)N_NODES * 128 * 2);
    ushort_t* vb0 = (ushort_t*)alloc((size_t)N_NODES * 128 * 2);
    ushort_t* vb1 = (ushort_t*)alloc((size_t)N_NODES * 128 * 2);
    float* sums0 = (float*)alloc(256 * 4);
    float* sums1 = (float*)alloc(256 * 4);
    float* sc0 = (float*)alloc(128 * 4);
    float* sh0 = (float*)alloc(128 * 4);
    float* sc1 = (float*)alloc(128 * 4);
    float* sh1 = (float*)alloc(128 * 4);
    (void)ws_size; (void)in_sizes; (void)n_in; (void)out_size;

    hipMemsetAsync(deg, 0, (size_t)NBINS * 4, stream);
    hipMemsetAsync(cnt, 0, (size_t)NBINS * 4, stream);
    hipMemsetAsync(sums0, 0, 256 * 4, stream);
    hipMemsetAsync(sums1, 0, 256 * 4, stream);

    prep_kernel<<<192, 256, 0, stream>>>(Wa1, W0, W1, Wa1b, W0b, W1b);
    x2b_kernel<<<6250, 256, 0, stream>>>(x, xb);

    // CSR by (set, dest)
    const int nscan = (NBINS + 1023) / 1024;  // 147
    hist_kernel<<<dim3(3125, 3), 256, 0, stream>>>(ei0, ei1, ei2, cnt);
    scan1_kernel<<<nscan, 1024, 0, stream>>>(cnt, offs, bsum);
    scan2_kernel<<<1, 256, 0, stream>>>(bsum, offs, nscan);
    scan3_kernel<<<nscan, 1024, 0, stream>>>(offs, bsum, cursor);
    fill_kernel<<<dim3(3125, 3), 256, 0, stream>>>(ei0, ei1, ei2, cursor, csr);

    // pipelined edge MLP (writes sigmoid w into csr.y, accumulates deg)
    edge_mlp_kernel<<<dim3(782, 3), 256, 0, stream>>>(xb, csr, Wa1b, ba1, Wa2, ba2, deg);
    dinv_kernel<<<(NBINS + 255) / 256, 256, 0, stream>>>(deg, dinv, NBINS);

    // combined per-node single-segment edge list with normalized weights
    offs2_kernel<<<(N_NODES + 256) / 256, 256, 0, stream>>>(offs, offs2);
    repack_kernel<<<12500, 256, 0, stream>>>(csr, offs, offs2, dinv, edges2);

    // layer 0
    gemm_rows_kernel<<<782, 256, 0, stream>>>(xb, W0b, hb, N_NODES);
    gather_spmm_kernel<<<12500, 256, 0, stream>>>(hb, offs2, edges2, b0, vb0);
    stats_kernel<<<512, 256, 0, stream>>>(vb0, sums0);
    finalize_stats_kernel<<<1, 128, 0, stream>>>(sums0, g0, be0, sc0, sh0);

    // layer 1 (bn0+relu fused into A-fragment construction)
    gemm_bn_rows_kernel<<<782, 256, 0, stream>>>(vb0, sc0, sh0, W1b, hb, N_NODES);
    gather_spmm_kernel<<<12500, 256, 0, stream>>>(hb, offs2, edges2, b1, vb1);
    stats_kernel<<<512, 256, 0, stream>>>(vb1, sums1);
    finalize_stats_kernel<<<1, 128, 0, stream>>>(sums1, g1, be1, sc1, sh1);
    bn_final_kernel<<<512, 256, 0, stream>>>(vb1, sc1, sh1, x, out);
}